// Round 14
// baseline (396.111 us; speedup 1.0000x reference)
//
#include <hip/hip_runtime.h>
#include <cstdint>
#include <cstddef>

// SLAYER SRM-alpha constants, rounded-to-nearest f32 from double
#define THETA_F 10.0f
#define DS_C 0.9048374180359595731642491f   // exp(-0.1)
#define DR_C 0.3678794411714423215955238f   // exp(-1.0)
#define CS_C 0.2718281828459045235360287f   // e/10
#define CR_C -54.3656365691809047072057f    // -2*10*e
#define P40_C 1.8315638888734179e-02f       // ds^40 = e^-4
#define Q40_C 6.6290701607045023e-01f       // 40 * ds^41 = 40*e^-4.1

typedef unsigned int       u32;
typedef unsigned long long u64;
typedef unsigned short     u16;

// ws layout (8,192,000 bytes = 64*512*2000 bits):
//   w32 region : u32 [64][62][512]  layer-1 spike bits, t in [tb*32,tb*32+32)
//   tail region: u16 [64][512] at byte offset 8,126,464, bits t in [1984,2000)
#define W32_WORDS_PER_B  (62 * 512)
#define TAIL_BYTE_OFF    (64 * 62 * 512 * 4)

// ---------------------------------------------------------------------------
// K1: layer-1 fc + psp_spike — SERIAL, bit-exact. BYTE-IDENTICAL to the
// R10/R12-validated kernel (86-88 µs). Own kernel: R13 proved fusing it
// degrades its codegen (VGPR 32->88, 3x slower). Established floor.
// ---------------------------------------------------------------------------
__global__ __launch_bounds__(128) void k1_layer1(
    const float* __restrict__ inp,                 // [64][4][2000]
    const float* __restrict__ W1,                  // [512][4]
    u32* __restrict__ w32, u16* __restrict__ tail16)
{
    __shared__ float table[16 * 128];
    __shared__ alignas(8) unsigned char codes[2048];

    const int tid = threadIdx.x;                   // 0..127
    const int b   = blockIdx.x >> 2;               // 0..63
    const int h   = ((blockIdx.x & 3) << 7) + tid; // 0..511

    const float w0 = W1[h * 4 + 0];
    const float w1 = W1[h * 4 + 1];
    const float w2 = W1[h * 4 + 2];
    const float w3 = W1[h * 4 + 3];
    for (int c = 0; c < 16; ++c) {
        float v = __fmul_rn(w0, (c & 1) ? 1.0f : 0.0f);
        v = __fadd_rn(v, __fmul_rn(w1, (c & 2) ? 1.0f : 0.0f));
        v = __fadd_rn(v, __fmul_rn(w2, (c & 4) ? 1.0f : 0.0f));
        v = __fadd_rn(v, __fmul_rn(w3, (c & 8) ? 1.0f : 0.0f));
        table[c * 128 + tid] = v;
    }
    for (int t = tid; t < 2000; t += 128) {
        const float v0 = inp[(b * 4 + 0) * 2000 + t];
        const float v1 = inp[(b * 4 + 1) * 2000 + t];
        const float v2 = inp[(b * 4 + 2) * 2000 + t];
        const float v3 = inp[(b * 4 + 3) * 2000 + t];
        codes[t] = (unsigned char)((int)(v0 != 0.0f) | ((int)(v1 != 0.0f) << 1) |
                                   ((int)(v2 != 0.0f) << 2) | ((int)(v3 != 0.0f) << 3));
    }
    if (tid < 48) codes[2000 + tid] = 0;   // pad
    __syncthreads();

#define ISSUE(CW, BUF) do {                                                   \
        const u32 lo_ = (u32)(CW), hi_ = (u32)((CW) >> 32);                   \
        BUF[0] = table[((lo_      ) & 15) * 128 + tid];                       \
        BUF[1] = table[((lo_ >>  8) & 15) * 128 + tid];                       \
        BUF[2] = table[((lo_ >> 16) & 15) * 128 + tid];                       \
        BUF[3] = table[((lo_ >> 24) & 15) * 128 + tid];                       \
        BUF[4] = table[((hi_      ) & 15) * 128 + tid];                       \
        BUF[5] = table[((hi_ >>  8) & 15) * 128 + tid];                       \
        BUF[6] = table[((hi_ >> 16) & 15) * 128 + tid];                       \
        BUF[7] = table[((hi_ >> 24) & 15) * 128 + tid];                       \
    } while (0)

#define STEP(AV, BITPOS) do {                                                 \
        const float u_ = __fadd_rn(__fmul_rn(CS_C, ys), __fmul_rn(CR_C, yr)); \
        const bool sp_ = (u_ >= THETA_F);                                     \
        xs = __fadd_rn(__fmul_rn(DS_C, xs), (AV));                            \
        ys = __fmul_rn(DS_C, __fadd_rn(ys, xs));                              \
        const float A_ = __fmul_rn(DR_C, xr);                                 \
        xr = sp_ ? __fadd_rn(A_, 1.0f) : A_;                                  \
        yr = __fmul_rn(DR_C, __fadd_rn(yr, xr));                              \
        bits = sp_ ? (bits | (1u << (BITPOS))) : bits;                        \
    } while (0)

#define STEP8(BUF, J0) do {                                                   \
        _Pragma("unroll")                                                     \
        for (int j_ = 0; j_ < 8; ++j_) STEP(BUF[j_], (J0) + j_);              \
    } while (0)

    float xs = 0.0f, ys = 0.0f, xr = 0.0f, yr = 0.0f;
    u32 bits = 0;
    u32* pw = w32 + (size_t)b * W32_WORDS_PER_B + h;

    float bA[8], bB[8];
    u64 cw = *reinterpret_cast<const u64*>(codes);
    ISSUE(cw, bA);
    u64 c1 = *reinterpret_cast<const u64*>(codes + 8);
    u64 c2 = *reinterpret_cast<const u64*>(codes + 16);
    u64 c3 = *reinterpret_cast<const u64*>(codes + 24);
    u64 c4 = *reinterpret_cast<const u64*>(codes + 32);

    for (int t0 = 0; t0 < 1984; t0 += 32) {
        ISSUE(c1, bB);
        const u64 n1 = *reinterpret_cast<const u64*>(codes + t0 + 40);
        const u64 n2 = *reinterpret_cast<const u64*>(codes + t0 + 48);
        const u64 n3 = *reinterpret_cast<const u64*>(codes + t0 + 56);
        const u64 n4 = *reinterpret_cast<const u64*>(codes + t0 + 64);
        STEP8(bA, 0);
        ISSUE(c2, bA);
        STEP8(bB, 8);
        ISSUE(c3, bB);
        STEP8(bA, 16);
        ISSUE(c4, bA);
        STEP8(bB, 24);
        *pw = bits; pw += 512; bits = 0;
        c1 = n1; c2 = n2; c3 = n3; c4 = n4;
    }
    ISSUE(c1, bB);
    STEP8(bA, 0);
    STEP8(bB, 8);
    tail16[b * 512 + h] = (u16)bits;

#undef STEP8
#undef STEP
#undef ISSUE
}

// ---------------------------------------------------------------------------
// K23: fc2 + full layer-2 tail in ONE kernel, one block per b (64 x 256).
// No grid sync needed: this block's chains {2b,2b+1} depend only on w32[b].
//  Phase A = R12 k2_fc2 arithmetic (identical per-output ascending-h cndmask
//    loop), 8 passes of 250 t, stage re-filled per pass; a2 kept in LDS.
//  Phase B = R12 k3all arithmetic (validated 40-chunk machinery), 2 chains:
//    lc = tid>>7, ck = tid&127 (active ck<50); a2 read from LDS (bit-
//    preserving), final psp written to global out.
// LDS arena ~45 KB; stage region overlaid by U after phase A (sync-guarded).
// ---------------------------------------------------------------------------
__global__ __launch_bounds__(256) void k23(
    const u32* __restrict__ w32, const u16* __restrict__ tail16,
    const float* __restrict__ W2,                  // [2][512]
    float* __restrict__ out)                       // [128][2000]
{
    __shared__ alignas(16) char smem[46208];
    float* w2s        = (float*)smem;                    // 1024 f32
    float* a2L        = (float*)(smem + 4096);           // [2][2000] f32
    unsigned char* s2 = (unsigned char*)(smem + 20096);  // [2][2000] B
    float* exa        = (float*)(smem + 24096);          // [2][50]
    float* eya        = (float*)(smem + 24496);
    float* pxa        = (float*)(smem + 24896);
    float* pya        = (float*)(smem + 25296);
    u32*   stage      = (u32*)(smem + 25728);            // 10*512 u32 (phase A)
    float* U          = (float*)(smem + 25728);          // [2][2000] (phase B)

    const int tid = threadIdx.x;                   // 0..255
    const int b   = blockIdx.x;                    // 0..63

    for (int j = tid; j < 1024; j += 256) w2s[j] = W2[j];

    // ================= phase A: a2 (both o) for this b, into LDS ===========
    for (int p = 0; p < 8; ++p) {
        const int t_lo  = p * 250;
        const int tb_lo = t_lo >> 5;
        const int tb_hi = (t_lo + 249) >> 5;
        const int nst   = (tb_hi - tb_lo + 1) << 9;
        __syncthreads();                           // protect stage reuse
        for (int idx = tid; idx < nst; idx += 256) {
            const int gtb = tb_lo + (idx >> 9);
            const int hh  = idx & 511;
            u32 v = 0;
            if (gtb < 62)       v = w32[((size_t)b * 62 + gtb) * 512 + hh];
            else if (gtb == 62) v = (u32)tail16[b * 512 + hh];
            stage[idx] = v;
        }
        __syncthreads();
        if (tid < 250) {
            const int t = t_lo + tid;
            const u32* srow = stage + (((t >> 5) - tb_lo) << 9);
            const int sh = t & 31;
            float acc0 = 0.0f, acc1 = 0.0f;
            #pragma unroll 8
            for (int hh = 0; hh < 512; ++hh) {
                const bool on = (srow[hh] >> sh) & 1u;
                acc0 = __fadd_rn(acc0, on ? w2s[hh] : 0.0f);
                acc1 = __fadd_rn(acc1, on ? w2s[512 + hh] : 0.0f);
            }
            a2L[t] = acc0;
            a2L[2000 + t] = acc1;
        }
    }
    __syncthreads();

    // ================= phase B: layer-2 + readout (validated machinery) ====
    const int lc = tid >> 7;                       // chain-local 0..1
    const int ck = tid & 127;                      // chunk, active if < 50
    const int chain = b * 2 + lc;
    float* ex = exa + lc * 50;  float* ey = eya + lc * 50;
    float* px = pxa + lc * 50;  float* py = pya + lc * 50;

    // ---- B.0: a2 -> U (zero-state + M^40 prefix + correction) ----
    if (ck < 50) {
        const float* segi = a2L + lc * 2000 + ck * 40;
        float* segU = U + lc * 2000 + ck * 40;
        float X = 0.0f, Y = 0.0f;
        for (int g = 0; g < 10; ++g) {
            float4 qv = *reinterpret_cast<const float4*>(segi + 4 * g);
            float z;
            z = __fmul_rn(CS_C, Y); X = __fmaf_rn(DS_C, X, qv.x);
            Y = __fmul_rn(DS_C, __fadd_rn(Y, X)); qv.x = z;
            z = __fmul_rn(CS_C, Y); X = __fmaf_rn(DS_C, X, qv.y);
            Y = __fmul_rn(DS_C, __fadd_rn(Y, X)); qv.y = z;
            z = __fmul_rn(CS_C, Y); X = __fmaf_rn(DS_C, X, qv.z);
            Y = __fmul_rn(DS_C, __fadd_rn(Y, X)); qv.z = z;
            z = __fmul_rn(CS_C, Y); X = __fmaf_rn(DS_C, X, qv.w);
            Y = __fmul_rn(DS_C, __fadd_rn(Y, X)); qv.w = z;
            *reinterpret_cast<float4*>(segU + 4 * g) = qv;
        }
        ex[ck] = X; ey[ck] = Y;
    }
    __syncthreads();
    if (ck == 0) {
        float x = 0.0f, y = 0.0f;
        for (int c = 0; c < 50; ++c) {
            px[c] = x; py[c] = y;
            const float xn = __fmaf_rn(P40_C, x, ex[c]);
            const float yn = __fadd_rn(
                __fmaf_rn(Q40_C, x, __fmul_rn(P40_C, y)), ey[c]);
            x = xn; y = yn;
        }
    }
    __syncthreads();
    if (ck >= 1 && ck < 50) {
        float xh = px[ck], yh = py[ck];
        float* segU = U + lc * 2000 + ck * 40;
        for (int g = 0; g < 10; ++g) {
            float4 qv = *reinterpret_cast<const float4*>(segU + 4 * g);
            qv.x = __fmaf_rn(CS_C, yh, qv.x);
            xh = __fmul_rn(DS_C, xh); yh = __fmul_rn(DS_C, __fadd_rn(yh, xh));
            qv.y = __fmaf_rn(CS_C, yh, qv.y);
            xh = __fmul_rn(DS_C, xh); yh = __fmul_rn(DS_C, __fadd_rn(yh, xh));
            qv.z = __fmaf_rn(CS_C, yh, qv.z);
            xh = __fmul_rn(DS_C, xh); yh = __fmul_rn(DS_C, __fadd_rn(yh, xh));
            qv.w = __fmaf_rn(CS_C, yh, qv.w);
            xh = __fmul_rn(DS_C, xh); yh = __fmul_rn(DS_C, __fadd_rn(yh, xh));
            *reinterpret_cast<float4*>(segU + 4 * g) = qv;
        }
    }
    __syncthreads();

    // ---- B.1: U -> s2 bytes (refractory warm-up + emit) ----
    if (ck < 50) {
        float xr2 = 0.0f, yr2 = 0.0f;
#define RSTEP(UV) do {                                                        \
        const float u_ = __fadd_rn((UV), __fmul_rn(CR_C, yr2));               \
        const bool sp_ = (u_ >= THETA_F);                                     \
        const float A_ = __fmul_rn(DR_C, xr2);                                \
        xr2 = sp_ ? __fadd_rn(A_, 1.0f) : A_;                                 \
        yr2 = __fmul_rn(DR_C, __fadd_rn(yr2, xr2));                           \
    } while (0)
        if (ck == 1) {                             // EXACT: warm from t=0
            const float* wseg = U + lc * 2000;
            #pragma unroll
            for (int g = 0; g < 10; ++g) {
                const float4 qv = *reinterpret_cast<const float4*>(wseg + 4 * g);
                RSTEP(qv.x); RSTEP(qv.y); RSTEP(qv.z); RSTEP(qv.w);
            }
        } else if (ck >= 2) {                      // 64-step warm (validated)
            const float* wseg = U + lc * 2000 + ck * 40 - 64;
            #pragma unroll
            for (int g = 0; g < 16; ++g) {
                const float4 qv = *reinterpret_cast<const float4*>(wseg + 4 * g);
                RSTEP(qv.x); RSTEP(qv.y); RSTEP(qv.z); RSTEP(qv.w);
            }
        }
        const float* eseg = U + lc * 2000 + ck * 40;
        unsigned char* ob = s2 + lc * 2000 + ck * 40;
        for (int g = 0; g < 10; ++g) {
            const float4 qv = *reinterpret_cast<const float4*>(eseg + 4 * g);
            const float uv[4] = {qv.x, qv.y, qv.z, qv.w};
            #pragma unroll
            for (int j = 0; j < 4; ++j) {
                const float u_ = __fadd_rn(uv[j], __fmul_rn(CR_C, yr2));
                const bool sp_ = (u_ >= THETA_F);
                ob[4 * g + j] = sp_ ? 1 : 0;
                const float A_ = __fmul_rn(DR_C, xr2);
                xr2 = sp_ ? __fadd_rn(A_, 1.0f) : A_;
                yr2 = __fmul_rn(DR_C, __fadd_rn(yr2, xr2));
            }
        }
#undef RSTEP
    }
    __syncthreads();

    // ---- B.2: s2 -> out (final psp readout) ----
    if (ck < 50) {
        float* sego = out + (size_t)chain * 2000 + ck * 40;
        const unsigned char* si = s2 + lc * 2000 + ck * 40;
        float X = 0.0f, Y = 0.0f;
        for (int j = 0; j < 40; ++j) {
            const float a = (float)si[j];
            const float z = __fmul_rn(CS_C, Y);
            X = __fmaf_rn(DS_C, X, a);
            Y = __fmul_rn(DS_C, __fadd_rn(Y, X));
            sego[j] = z;
        }
        ex[ck] = X; ey[ck] = Y;
    }
    __syncthreads();
    if (ck == 0) {
        float x = 0.0f, y = 0.0f;
        for (int c = 0; c < 50; ++c) {
            px[c] = x; py[c] = y;
            const float xn = __fmaf_rn(P40_C, x, ex[c]);
            const float yn = __fadd_rn(
                __fmaf_rn(Q40_C, x, __fmul_rn(P40_C, y)), ey[c]);
            x = xn; y = yn;
        }
    }
    __syncthreads();
    if (ck >= 1 && ck < 50) {
        float* sego = out + (size_t)chain * 2000 + ck * 40;
        float xh = px[ck], yh = py[ck];
        for (int j = 0; j < 40; ++j) {
            sego[j] = __fmaf_rn(CS_C, yh, sego[j]);
            xh = __fmul_rn(DS_C, xh);
            yh = __fmul_rn(DS_C, __fadd_rn(yh, xh));
        }
    }
}

extern "C" void kernel_launch(void* const* d_in, const int* in_sizes, int n_in,
                              void* d_out, int out_size, void* d_ws, size_t ws_size,
                              hipStream_t stream)
{
    const float* inp = (const float*)d_in[0];  // [64][4][2000]
    const float* W1  = (const float*)d_in[1];  // [512][4]
    const float* W2  = (const float*)d_in[2];  // [2][512]
    float* out = (float*)d_out;                // [64][2][2000]

    u32* w32    = (u32*)d_ws;
    u16* tail16 = (u16*)((char*)d_ws + TAIL_BYTE_OFF);

    k1_layer1<<<dim3(256), dim3(128), 0, stream>>>(inp, W1, w32, tail16);
    k23<<<dim3(64), dim3(256), 0, stream>>>(w32, tail16, W2, out);
}

// Round 15
// 137.504 us; speedup vs baseline: 2.8807x; 2.8807x over previous
//
#include <hip/hip_runtime.h>
#include <cstdint>
#include <cstddef>

// SLAYER SRM-alpha constants, rounded-to-nearest f32 from double
#define THETA_F 10.0f
#define DS_C 0.9048374180359595731642491f   // exp(-0.1)
#define DR_C 0.3678794411714423215955238f   // exp(-1.0)
#define CS_C 0.2718281828459045235360287f   // e/10
#define CR_C -54.3656365691809047072057f    // -2*10*e
#define P40_C 1.8315638888734179e-02f       // ds^40 = e^-4
#define Q40_C 6.6290701607045023e-01f       // 40 * ds^41 = 40*e^-4.1

typedef unsigned int       u32;
typedef unsigned long long u64;
typedef unsigned short     u16;

// ws layout (8,192,000 bytes = 64*512*2000 bits):
//   w32 region : u32 [64][62][512]  layer-1 spike bits, t in [tb*32,tb*32+32)
//   tail region: u16 [64][512] at byte offset 8,126,464, bits t in [1984,2000)
#define W32_WORDS_PER_B  (62 * 512)
#define TAIL_BYTE_OFF    (64 * 62 * 512 * 4)

// ---------------------------------------------------------------------------
// K1: layer-1 fc + psp_spike — SERIAL, bit-exact (validated R5/R10/R12).
// Own kernel with typed __shared__ arrays: R13/R14 proved both fusion and
// char-arena LDS degrade codegen catastrophically. 86-88 µs = established
// floor (TLP R4, ILP R11, chunking R8/R9 all bracketed).
// ---------------------------------------------------------------------------
__global__ __launch_bounds__(128) void k1_layer1(
    const float* __restrict__ inp,                 // [64][4][2000]
    const float* __restrict__ W1,                  // [512][4]
    u32* __restrict__ w32, u16* __restrict__ tail16)
{
    __shared__ float table[16 * 128];
    __shared__ alignas(8) unsigned char codes[2048];

    const int tid = threadIdx.x;                   // 0..127
    const int b   = blockIdx.x >> 2;               // 0..63
    const int h   = ((blockIdx.x & 3) << 7) + tid; // 0..511

    const float w0 = W1[h * 4 + 0];
    const float w1 = W1[h * 4 + 1];
    const float w2 = W1[h * 4 + 2];
    const float w3 = W1[h * 4 + 3];
    for (int c = 0; c < 16; ++c) {
        float v = __fmul_rn(w0, (c & 1) ? 1.0f : 0.0f);
        v = __fadd_rn(v, __fmul_rn(w1, (c & 2) ? 1.0f : 0.0f));
        v = __fadd_rn(v, __fmul_rn(w2, (c & 4) ? 1.0f : 0.0f));
        v = __fadd_rn(v, __fmul_rn(w3, (c & 8) ? 1.0f : 0.0f));
        table[c * 128 + tid] = v;
    }
    for (int t = tid; t < 2000; t += 128) {
        const float v0 = inp[(b * 4 + 0) * 2000 + t];
        const float v1 = inp[(b * 4 + 1) * 2000 + t];
        const float v2 = inp[(b * 4 + 2) * 2000 + t];
        const float v3 = inp[(b * 4 + 3) * 2000 + t];
        codes[t] = (unsigned char)((int)(v0 != 0.0f) | ((int)(v1 != 0.0f) << 1) |
                                   ((int)(v2 != 0.0f) << 2) | ((int)(v3 != 0.0f) << 3));
    }
    if (tid < 48) codes[2000 + tid] = 0;   // pad
    __syncthreads();

#define ISSUE(CW, BUF) do {                                                   \
        const u32 lo_ = (u32)(CW), hi_ = (u32)((CW) >> 32);                   \
        BUF[0] = table[((lo_      ) & 15) * 128 + tid];                       \
        BUF[1] = table[((lo_ >>  8) & 15) * 128 + tid];                       \
        BUF[2] = table[((lo_ >> 16) & 15) * 128 + tid];                       \
        BUF[3] = table[((lo_ >> 24) & 15) * 128 + tid];                       \
        BUF[4] = table[((hi_      ) & 15) * 128 + tid];                       \
        BUF[5] = table[((hi_ >>  8) & 15) * 128 + tid];                       \
        BUF[6] = table[((hi_ >> 16) & 15) * 128 + tid];                       \
        BUF[7] = table[((hi_ >> 24) & 15) * 128 + tid];                       \
    } while (0)

#define STEP(AV, BITPOS) do {                                                 \
        const float u_ = __fadd_rn(__fmul_rn(CS_C, ys), __fmul_rn(CR_C, yr)); \
        const bool sp_ = (u_ >= THETA_F);                                     \
        xs = __fadd_rn(__fmul_rn(DS_C, xs), (AV));                            \
        ys = __fmul_rn(DS_C, __fadd_rn(ys, xs));                              \
        const float A_ = __fmul_rn(DR_C, xr);                                 \
        xr = sp_ ? __fadd_rn(A_, 1.0f) : A_;                                  \
        yr = __fmul_rn(DR_C, __fadd_rn(yr, xr));                              \
        bits = sp_ ? (bits | (1u << (BITPOS))) : bits;                        \
    } while (0)

#define STEP8(BUF, J0) do {                                                   \
        _Pragma("unroll")                                                     \
        for (int j_ = 0; j_ < 8; ++j_) STEP(BUF[j_], (J0) + j_);              \
    } while (0)

    float xs = 0.0f, ys = 0.0f, xr = 0.0f, yr = 0.0f;
    u32 bits = 0;
    u32* pw = w32 + (size_t)b * W32_WORDS_PER_B + h;

    float bA[8], bB[8];
    u64 cw = *reinterpret_cast<const u64*>(codes);
    ISSUE(cw, bA);
    u64 c1 = *reinterpret_cast<const u64*>(codes + 8);
    u64 c2 = *reinterpret_cast<const u64*>(codes + 16);
    u64 c3 = *reinterpret_cast<const u64*>(codes + 24);
    u64 c4 = *reinterpret_cast<const u64*>(codes + 32);

    for (int t0 = 0; t0 < 1984; t0 += 32) {
        ISSUE(c1, bB);
        const u64 n1 = *reinterpret_cast<const u64*>(codes + t0 + 40);
        const u64 n2 = *reinterpret_cast<const u64*>(codes + t0 + 48);
        const u64 n3 = *reinterpret_cast<const u64*>(codes + t0 + 56);
        const u64 n4 = *reinterpret_cast<const u64*>(codes + t0 + 64);
        STEP8(bA, 0);
        ISSUE(c2, bA);
        STEP8(bB, 8);
        ISSUE(c3, bB);
        STEP8(bA, 16);
        ISSUE(c4, bA);
        STEP8(bB, 24);
        *pw = bits; pw += 512; bits = 0;
        c1 = n1; c2 = n2; c3 = n3; c4 = n4;
    }
    ISSUE(c1, bB);
    STEP8(bA, 0);
    STEP8(bB, 8);
    tail16[b * 512 + h] = (u16)bits;

#undef STEP8
#undef STEP
#undef ISSUE
}

// ---------------------------------------------------------------------------
// K2: a2[b,o,t] = ascending-h sum of W2[o,h]*s1[b,h,t] (byte-identical, valid.)
// ---------------------------------------------------------------------------
__global__ __launch_bounds__(256) void k2_fc2(
    const u32* __restrict__ w32, const u16* __restrict__ tail16,
    const float* __restrict__ W2,                  // [2][512]
    float* __restrict__ a2)                        // [128][2000]
{
    __shared__ float w2s[1024];
    __shared__ u32 stage[4096];                    // [local tb 0..7][h 0..511]

    const int tid = threadIdx.x;
    const int b  = blockIdx.x >> 3;
    const int it = blockIdx.x & 7;

    for (int j = tid; j < 1024; j += 256) w2s[j] = W2[j];
    #pragma unroll
    for (int k = 0; k < 16; ++k) {
        const int l = tid + (k << 8);              // 0..4095
        const int gtb = (it << 3) + (l >> 9);
        u32 v = 0;
        if (gtb < 62)       v = w32[((size_t)b * 62 + gtb) * 512 + (l & 511)];
        else if (gtb == 62) v = (u32)tail16[b * 512 + (l & 511)];
        stage[l] = v;
    }
    __syncthreads();

    const int t = (it << 8) + tid;
    if (t < 2000) {
        const u32* srow = stage + ((tid >> 5) << 9);
        const int sh = tid & 31;
        float acc0 = 0.0f, acc1 = 0.0f;
        #pragma unroll 8
        for (int hh = 0; hh < 512; ++hh) {
            const bool on = (srow[hh] >> sh) & 1u;
            acc0 = __fadd_rn(acc0, on ? w2s[hh] : 0.0f);
            acc1 = __fadd_rn(acc1, on ? w2s[512 + hh] : 0.0f);
        }
        a2[(size_t)(b * 2 + 0) * 2000 + t] = acc0;
        a2[(size_t)(b * 2 + 1) * 2000 + t] = acc1;
    }
}

// ---------------------------------------------------------------------------
// K3all: merged tail, 50 chunks of 40 steps (validated R12). Typed __shared__
// arrays. k3lin zero-state + M^40 prefix + correction; spike gen with
// refractory warm-up (ck=1 exact from t=0; ck>=2 64-step warm); final psp.
// grid 32 x block 200 (4 chains x 50 chunks).
// ---------------------------------------------------------------------------
__global__ __launch_bounds__(200) void k3all(
    const float* __restrict__ a2, float* __restrict__ out)
{
    __shared__ float U[4][2000];
    __shared__ unsigned char s2b[4][2000];
    __shared__ float ex[4][50], ey[4][50], px[4][50], py[4][50];

    const int tid = threadIdx.x;                   // 0..199
    const int lc  = tid / 50;                      // 0..3
    const int ck  = tid - lc * 50;                 // 0..49
    const int chain = blockIdx.x * 4 + lc;         // 0..127

    // ---- phase 0: a2 -> U (zero-state alpha filter per 40-chunk) ----
    {
        const float* segi = a2 + (size_t)chain * 2000 + ck * 40;
        float* segU = &U[lc][ck * 40];
        float X = 0.0f, Y = 0.0f;
        for (int g = 0; g < 10; ++g) {
            float4 qv = *reinterpret_cast<const float4*>(segi + 4 * g);
            float z;
            z = __fmul_rn(CS_C, Y); X = __fmaf_rn(DS_C, X, qv.x);
            Y = __fmul_rn(DS_C, __fadd_rn(Y, X)); qv.x = z;
            z = __fmul_rn(CS_C, Y); X = __fmaf_rn(DS_C, X, qv.y);
            Y = __fmul_rn(DS_C, __fadd_rn(Y, X)); qv.y = z;
            z = __fmul_rn(CS_C, Y); X = __fmaf_rn(DS_C, X, qv.z);
            Y = __fmul_rn(DS_C, __fadd_rn(Y, X)); qv.z = z;
            z = __fmul_rn(CS_C, Y); X = __fmaf_rn(DS_C, X, qv.w);
            Y = __fmul_rn(DS_C, __fadd_rn(Y, X)); qv.w = z;
            *reinterpret_cast<float4*>(segU + 4 * g) = qv;
        }
        ex[lc][ck] = X; ey[lc][ck] = Y;
    }
    __syncthreads();
    if (tid < 4) {                                 // M^40 prefix over 50 chunks
        float x = 0.0f, y = 0.0f;
        for (int c = 0; c < 50; ++c) {
            px[tid][c] = x; py[tid][c] = y;
            const float xn = __fmaf_rn(P40_C, x, ex[tid][c]);
            const float yn = __fadd_rn(
                __fmaf_rn(Q40_C, x, __fmul_rn(P40_C, y)), ey[tid][c]);
            x = xn; y = yn;
        }
    }
    __syncthreads();
    {
        float xh = px[lc][ck], yh = py[lc][ck];
        float* segU = &U[lc][ck * 40];
        if (ck != 0) {                             // homogeneous correction
            for (int g = 0; g < 10; ++g) {
                float4 qv = *reinterpret_cast<const float4*>(segU + 4 * g);
                qv.x = __fmaf_rn(CS_C, yh, qv.x);
                xh = __fmul_rn(DS_C, xh); yh = __fmul_rn(DS_C, __fadd_rn(yh, xh));
                qv.y = __fmaf_rn(CS_C, yh, qv.y);
                xh = __fmul_rn(DS_C, xh); yh = __fmul_rn(DS_C, __fadd_rn(yh, xh));
                qv.z = __fmaf_rn(CS_C, yh, qv.z);
                xh = __fmul_rn(DS_C, xh); yh = __fmul_rn(DS_C, __fadd_rn(yh, xh));
                qv.w = __fmaf_rn(CS_C, yh, qv.w);
                xh = __fmul_rn(DS_C, xh); yh = __fmul_rn(DS_C, __fadd_rn(yh, xh));
                *reinterpret_cast<float4*>(segU + 4 * g) = qv;
            }
        }
    }
    __syncthreads();

    // ---- phase 1: U -> s2 bytes (refractory warm-up + emit) ----
    {
        float xr2 = 0.0f, yr2 = 0.0f;
#define RSTEP(UV) do {                                                        \
        const float u_ = __fadd_rn((UV), __fmul_rn(CR_C, yr2));               \
        const bool sp_ = (u_ >= THETA_F);                                     \
        const float A_ = __fmul_rn(DR_C, xr2);                                \
        xr2 = sp_ ? __fadd_rn(A_, 1.0f) : A_;                                 \
        yr2 = __fmul_rn(DR_C, __fadd_rn(yr2, xr2));                           \
    } while (0)
        if (ck == 1) {                             // EXACT: warm from t=0
            const float* wseg = &U[lc][0];
            #pragma unroll
            for (int g = 0; g < 10; ++g) {
                const float4 qv = *reinterpret_cast<const float4*>(wseg + 4 * g);
                RSTEP(qv.x); RSTEP(qv.y); RSTEP(qv.z); RSTEP(qv.w);
            }
        } else if (ck >= 2) {                      // 64-step warm (validated)
            const float* wseg = &U[lc][ck * 40 - 64];
            #pragma unroll
            for (int g = 0; g < 16; ++g) {
                const float4 qv = *reinterpret_cast<const float4*>(wseg + 4 * g);
                RSTEP(qv.x); RSTEP(qv.y); RSTEP(qv.z); RSTEP(qv.w);
            }
        }
        const float* eseg = &U[lc][ck * 40];
        unsigned char* ob = &s2b[lc][ck * 40];
        for (int g = 0; g < 10; ++g) {
            const float4 qv = *reinterpret_cast<const float4*>(eseg + 4 * g);
            const float uv[4] = {qv.x, qv.y, qv.z, qv.w};
            #pragma unroll
            for (int j = 0; j < 4; ++j) {
                const float u_ = __fadd_rn(uv[j], __fmul_rn(CR_C, yr2));
                const bool sp_ = (u_ >= THETA_F);
                ob[4 * g + j] = sp_ ? 1 : 0;
                const float A_ = __fmul_rn(DR_C, xr2);
                xr2 = sp_ ? __fadd_rn(A_, 1.0f) : A_;
                yr2 = __fmul_rn(DR_C, __fadd_rn(yr2, xr2));
            }
        }
#undef RSTEP
    }
    __syncthreads();

    // ---- phase 2: s2 -> out (final psp readout, same chunked filter) ----
    float* sego = out + (size_t)chain * 2000 + ck * 40;
    {
        const unsigned char* si = &s2b[lc][ck * 40];
        float X = 0.0f, Y = 0.0f;
        for (int j = 0; j < 40; ++j) {
            const float a = (float)si[j];
            const float z = __fmul_rn(CS_C, Y);
            X = __fmaf_rn(DS_C, X, a);
            Y = __fmul_rn(DS_C, __fadd_rn(Y, X));
            sego[j] = z;
        }
        ex[lc][ck] = X; ey[lc][ck] = Y;
    }
    __syncthreads();
    if (tid < 4) {
        float x = 0.0f, y = 0.0f;
        for (int c = 0; c < 50; ++c) {
            px[tid][c] = x; py[tid][c] = y;
            const float xn = __fmaf_rn(P40_C, x, ex[tid][c]);
            const float yn = __fadd_rn(
                __fmaf_rn(Q40_C, x, __fmul_rn(P40_C, y)), ey[tid][c]);
            x = xn; y = yn;
        }
    }
    __syncthreads();
    {
        float xh = px[lc][ck], yh = py[lc][ck];
        if (ck != 0) {
            for (int j = 0; j < 40; ++j) {
                sego[j] = __fmaf_rn(CS_C, yh, sego[j]);
                xh = __fmul_rn(DS_C, xh);
                yh = __fmul_rn(DS_C, __fadd_rn(yh, xh));
            }
        }
    }
}

extern "C" void kernel_launch(void* const* d_in, const int* in_sizes, int n_in,
                              void* d_out, int out_size, void* d_ws, size_t ws_size,
                              hipStream_t stream)
{
    const float* inp = (const float*)d_in[0];  // [64][4][2000]
    const float* W1  = (const float*)d_in[1];  // [512][4]
    const float* W2  = (const float*)d_in[2];  // [2][512]
    float* out = (float*)d_out;                // [64][2][2000]

    u32* w32    = (u32*)d_ws;
    u16* tail16 = (u16*)((char*)d_ws + TAIL_BYTE_OFF);

    k1_layer1<<<dim3(256), dim3(128), 0, stream>>>(inp, W1, w32, tail16);
    k2_fc2<<<dim3(512), dim3(256), 0, stream>>>(w32, tail16, W2, out);
    k3all<<<dim3(32), dim3(200), 0, stream>>>(out, out);
}